// Round 2
// baseline (386.974 us; speedup 1.0000x reference)
//
#include <hip/hip_runtime.h>
#include <math.h>

#define B_ 1024
#define G_ 256
#define K_ 256
#define E_ 64

// ws layout (in floats)
#define OFF_Q6  ((size_t)0)                          // K*E*E
#define OFF_V   ((size_t)(K_ * E_ * E_))             // K*E
#define OFF_VT  (OFF_V + (size_t)K_ * E_)            // K*E  (vtilde = Lhat^T v)
#define OFF_MSQ (OFF_VT + (size_t)K_ * E_)           // K
#define OFF_LIN (OFF_MSQ + (size_t)K_)               // B*K
#define OFF_SC  (OFF_LIN + (size_t)B_ * K_)          // B*K
#define OFF_WT  (OFF_SC + (size_t)B_ * K_)           // K*G*E (Wtilde = W * Lhat)

struct CoefF { float c5[6]; float c6[6]; };

// ---------------------------------------------------------------------------
// pre: per k (grid K, block 256):
//   A = W^T W, v = W^T m, msq = ||m||^2
//   P5 = sum_{i<5} M^i, Q6 = beta * sum_{i<6} M^i  (M = (1-b)I - b A)
//   N = 2b P5 - b^2 P5 A P5  (= -S, SPD) ; LDL^T ; Lhat = L sqrt(D)
//   Wtilde = W Lhat ; vtilde = Lhat^T v
__global__ __launch_bounds__(256) void pre_kernel(const float* __restrict__ w,
                                                  const float* __restrict__ mu,
                                                  float* __restrict__ ws, CoefF cf) {
    const int k = blockIdx.x;
    const int t = threadIdx.x;
    const int ti = t >> 4, tj = t & 15;
    __shared__ __align__(16) float sW[64 * 65];
    __shared__ float bufA[64 * 65];
    __shared__ float bufP[64 * 65];
    __shared__ float bufL[64 * 65];
    __shared__ float sV[64];
    __shared__ float dred[256];

    // ---- phase A: A = W^T W, v, msq ----
    float acc[4][4];
#pragma unroll
    for (int a = 0; a < 4; ++a)
#pragma unroll
        for (int b = 0; b < 4; ++b) acc[a][b] = 0.f;
    float vacc = 0.f, msqacc = 0.f;
    const int e_t = t & 63, p_t = t >> 6;

    for (int gc = 0; gc < 4; ++gc) {
        __syncthreads();
#pragma unroll
        for (int i = 0; i < 16; ++i) {
            int lin = t + 256 * i;
            int gg = lin >> 6, e = lin & 63;
            sW[gg * 65 + e] = w[((size_t)k * G_ + gc * 64 + gg) * E_ + e];
        }
        if (t < 64) dred[t] = mu[(size_t)(gc * 64 + t) * K_ + k];  // mu chunk
        __syncthreads();
#pragma unroll 4
        for (int gg = 0; gg < 64; ++gg) {
            float ra[4], rb[4];
#pragma unroll
            for (int a = 0; a < 4; ++a) ra[a] = sW[gg * 65 + ti * 4 + a];
#pragma unroll
            for (int b = 0; b < 4; ++b) rb[b] = sW[gg * 65 + tj * 4 + b];
#pragma unroll
            for (int a = 0; a < 4; ++a)
#pragma unroll
                for (int b = 0; b < 4; ++b) acc[a][b] += ra[a] * rb[b];
        }
        for (int gg = p_t * 16; gg < p_t * 16 + 16; ++gg)
            vacc += sW[gg * 65 + e_t] * dred[gg];
        if (t == 255) {
            for (int gg = 0; gg < 64; ++gg) msqacc += dred[gg] * dred[gg];
        }
    }
    __syncthreads();
#pragma unroll
    for (int a = 0; a < 4; ++a)
#pragma unroll
        for (int b = 0; b < 4; ++b)
            bufA[(ti * 4 + a) * 65 + tj * 4 + b] = acc[a][b];
    if (t == 255) ws[OFF_MSQ + k] = msqacc;
    // v reduction: vacc partials live per-thread; stash via bufP (free now)
    bufP[t] = vacc;
    __syncthreads();
    if (t < 64) {
        float v = bufP[t] + bufP[t + 64] + bufP[t + 128] + bufP[t + 192];
        sV[t] = v;
        ws[OFF_V + (size_t)k * 64 + t] = v;
    }
    __syncthreads();

    // ---- polynomial in A ----
    float acc5[4][4], acc6[4][4];
#pragma unroll
    for (int a = 0; a < 4; ++a)
#pragma unroll
        for (int b = 0; b < 4; ++b) {
            int e = ti * 4 + a, f = tj * 4 + b;
            float av = bufA[e * 65 + f];
            float id = (e == f) ? 1.f : 0.f;
            acc5[a][b] = cf.c5[0] * id + cf.c5[1] * av;
            acc6[a][b] = cf.c6[0] * id + cf.c6[1] * av;
        }
    for (int j = 2; j <= 5; ++j) {
        const float* X = (j == 2) ? bufA : bufP;
        float pw[4][4];
#pragma unroll
        for (int a = 0; a < 4; ++a)
#pragma unroll
            for (int b = 0; b < 4; ++b) pw[a][b] = 0.f;
        for (int l = 0; l < 64; ++l) {
            float xa[4], yb[4];
#pragma unroll
            for (int a = 0; a < 4; ++a) xa[a] = X[(ti * 4 + a) * 65 + l];
#pragma unroll
            for (int b = 0; b < 4; ++b) yb[b] = bufA[l * 65 + tj * 4 + b];
#pragma unroll
            for (int a = 0; a < 4; ++a)
#pragma unroll
                for (int b = 0; b < 4; ++b) pw[a][b] += xa[a] * yb[b];
        }
        __syncthreads();
#pragma unroll
        for (int a = 0; a < 4; ++a)
#pragma unroll
            for (int b = 0; b < 4; ++b)
                bufP[(ti * 4 + a) * 65 + tj * 4 + b] = pw[a][b];
        __syncthreads();
#pragma unroll
        for (int a = 0; a < 4; ++a)
#pragma unroll
            for (int b = 0; b < 4; ++b) {
                if (j <= 4) acc5[a][b] += cf.c5[j] * pw[a][b];
                acc6[a][b] += cf.c6[j] * pw[a][b];
            }
    }
    // Q6 = beta * acc6 -> global
    {
        float* gQ6 = ws + OFF_Q6 + (size_t)k * 4096;
#pragma unroll
        for (int a = 0; a < 4; ++a)
#pragma unroll
            for (int b = 0; b < 4; ++b)
                gQ6[(ti * 4 + a) * 64 + tj * 4 + b] = 0.05f * acc6[a][b];
    }
    // P5 -> bufL
    __syncthreads();
#pragma unroll
    for (int a = 0; a < 4; ++a)
#pragma unroll
        for (int b = 0; b < 4; ++b)
            bufL[(ti * 4 + a) * 65 + tj * 4 + b] = acc5[a][b];
    __syncthreads();
    // T = A * P5  (regs), then -> bufP
    {
        float tacc[4][4];
#pragma unroll
        for (int a = 0; a < 4; ++a)
#pragma unroll
            for (int b = 0; b < 4; ++b) tacc[a][b] = 0.f;
        for (int l = 0; l < 64; ++l) {
            float xa[4], yb[4];
#pragma unroll
            for (int a = 0; a < 4; ++a) xa[a] = bufA[(ti * 4 + a) * 65 + l];
#pragma unroll
            for (int b = 0; b < 4; ++b) yb[b] = bufL[l * 65 + tj * 4 + b];
#pragma unroll
            for (int a = 0; a < 4; ++a)
#pragma unroll
                for (int b = 0; b < 4; ++b) tacc[a][b] += xa[a] * yb[b];
        }
        __syncthreads();
#pragma unroll
        for (int a = 0; a < 4; ++a)
#pragma unroll
            for (int b = 0; b < 4; ++b)
                bufP[(ti * 4 + a) * 65 + tj * 4 + b] = tacc[a][b];
        __syncthreads();
    }
    // N = 2b*P5 - b^2 * (P5*T)  -> bufA (overwrite A)
    {
        float sacc[4][4];
#pragma unroll
        for (int a = 0; a < 4; ++a)
#pragma unroll
            for (int b = 0; b < 4; ++b) sacc[a][b] = 0.f;
        for (int l = 0; l < 64; ++l) {
            float xa[4], yb[4];
#pragma unroll
            for (int a = 0; a < 4; ++a) xa[a] = bufL[(ti * 4 + a) * 65 + l];
#pragma unroll
            for (int b = 0; b < 4; ++b) yb[b] = bufP[l * 65 + tj * 4 + b];
#pragma unroll
            for (int a = 0; a < 4; ++a)
#pragma unroll
                for (int b = 0; b < 4; ++b) sacc[a][b] += xa[a] * yb[b];
        }
        __syncthreads();
        const float beta = 0.05f;
#pragma unroll
        for (int a = 0; a < 4; ++a)
#pragma unroll
            for (int b = 0; b < 4; ++b)
                bufA[(ti * 4 + a) * 65 + tj * 4 + b] =
                    2.f * beta * acc5[a][b] - beta * beta * sacc[a][b];
    }
    // ---- LDL^T on bufA (lower triangle; diag never modified after its step) ----
    for (int j = 0; j < 64; ++j) {
        __syncthreads();
        float D = bufA[j * 65 + j];
        float invd = 1.0f / fmaxf(D, 1e-20f);
        for (int idx = t; idx < 4096; idx += 256) {
            int i = idx >> 6, l = idx & 63;
            if (i > j && l > j && l <= i)
                bufA[i * 65 + l] -= bufA[i * 65 + j] * bufA[l * 65 + j] * invd;
        }
    }
    __syncthreads();
    // Lhat: col e scaled by 1/sqrt(D_e) below diag, diag = sqrt(D_e) -> bufL
    for (int idx = t; idx < 4096; idx += 256) {
        int i = idx >> 6, e = idx & 63;
        float De = fmaxf(bufA[e * 65 + e], 1e-20f);
        float val;
        if (i > e)      val = bufA[i * 65 + e] / sqrtf(De);
        else if (i == e) val = sqrtf(De);
        else            val = 0.f;
        bufL[i * 65 + e] = val;
    }
    __syncthreads();
    // vtilde = Lhat^T v
    if (t < 64) {
        float s = 0.f;
        for (int f = 0; f < 64; ++f) s += sV[f] * bufL[f * 65 + t];
        ws[OFF_VT + (size_t)k * 64 + t] = s;
    }
    // ---- Wtilde = W * Lhat ----
    for (int rc = 0; rc < 4; ++rc) {
        __syncthreads();
#pragma unroll
        for (int i = 0; i < 16; ++i) {
            int lin = t + 256 * i;
            int gg = lin >> 6, e = lin & 63;
            sW[gg * 65 + e] = w[((size_t)k * G_ + rc * 64 + gg) * E_ + e];
        }
        __syncthreads();
        float wt[4][4];
#pragma unroll
        for (int a = 0; a < 4; ++a)
#pragma unroll
            for (int b = 0; b < 4; ++b) wt[a][b] = 0.f;
        for (int f = 0; f < 64; ++f) {
            float xa[4], yb[4];
#pragma unroll
            for (int a = 0; a < 4; ++a) xa[a] = sW[(ti * 4 + a) * 65 + f];
#pragma unroll
            for (int b = 0; b < 4; ++b) yb[b] = bufL[f * 65 + tj * 4 + b];
#pragma unroll
            for (int a = 0; a < 4; ++a)
#pragma unroll
                for (int b = 0; b < 4; ++b) wt[a][b] += xa[a] * yb[b];
        }
#pragma unroll
        for (int a = 0; a < 4; ++a) {
            float4 o = make_float4(wt[a][0], wt[a][1], wt[a][2], wt[a][3]);
            *(float4*)&ws[OFF_WT + ((size_t)k * G_ + rc * 64 + ti * 4 + a) * 64 + tj * 4] = o;
        }
    }
}

// ---------------------------------------------------------------------------
// L1: lin[b,k] = msq[k] - 2 * sum_g img[b,g]*mu[g,k]   (grid (16,4), block 256)
__global__ __launch_bounds__(256) void l1_kernel(const float* __restrict__ img,
                                                 const float* __restrict__ mu,
                                                 float* __restrict__ ws) {
    const int b0 = blockIdx.x * 64;
    const int k0 = blockIdx.y * 64;
    const int t = threadIdx.x;
    const int ti = t >> 4, tj = t & 15;
    __shared__ float sI[64 * 65];
    __shared__ float sM[64 * 65];
    float acc[4][4];
#pragma unroll
    for (int a = 0; a < 4; ++a)
#pragma unroll
        for (int b = 0; b < 4; ++b) acc[a][b] = 0.f;

    for (int gc = 0; gc < 4; ++gc) {
        if (gc) __syncthreads();
#pragma unroll
        for (int i = 0; i < 16; ++i) {
            int lin = t + 256 * i;
            int r = lin >> 6, c = lin & 63;
            sI[r * 65 + c] = img[(size_t)(b0 + r) * G_ + gc * 64 + c];
            sM[r * 65 + c] = mu[(size_t)(gc * 64 + r) * K_ + k0 + c];
        }
        __syncthreads();
#pragma unroll 4
        for (int gg = 0; gg < 64; ++gg) {
            float xa[4], yb[4];
#pragma unroll
            for (int a = 0; a < 4; ++a) xa[a] = sI[(ti * 4 + a) * 65 + gg];
#pragma unroll
            for (int b = 0; b < 4; ++b) yb[b] = sM[gg * 65 + tj * 4 + b];
#pragma unroll
            for (int a = 0; a < 4; ++a)
#pragma unroll
                for (int b = 0; b < 4; ++b) acc[a][b] += xa[a] * yb[b];
        }
    }
#pragma unroll
    for (int a = 0; a < 4; ++a)
#pragma unroll
        for (int b = 0; b < 4; ++b) {
            int kk = k0 + tj * 4 + b;
            ws[OFF_LIN + (size_t)(b0 + ti * 4 + a) * K_ + kk] =
                ws[OFF_MSQ + kk] - 2.0f * acc[a][b];
        }
}

// ---------------------------------------------------------------------------
// G1: per (k, 128-row b tile): T = img * Wtilde_k ;
//     score[b,k] = lin[b,k] - sum_e (T[b,e] - vtilde[e])^2
// grid (8, K), block 256
__global__ __launch_bounds__(256) void g1_kernel(const float* __restrict__ img,
                                                 float* __restrict__ ws) {
    const int k = blockIdx.y;
    const int b0 = blockIdx.x * 128;
    const int t = threadIdx.x;
    const int ti = t >> 4, tj = t & 15;
    __shared__ __align__(16) float imgT[32 * 132];
    __shared__ __align__(16) float sWt[32 * 68];
    __shared__ float sVt[64];
    const float* wt = ws + OFF_WT;

    if (t < 64) sVt[t] = ws[OFF_VT + (size_t)k * 64 + t];

    float acc[8][4];
#pragma unroll
    for (int a = 0; a < 8; ++a)
#pragma unroll
        for (int b = 0; b < 4; ++b) acc[a][b] = 0.f;

    for (int gc = 0; gc < 8; ++gc) {
        __syncthreads();
#pragma unroll
        for (int i = 0; i < 16; ++i) {
            int lin = t + 256 * i;
            int r = lin >> 5, gg = lin & 31;
            imgT[gg * 132 + r] = img[(size_t)(b0 + r) * G_ + gc * 32 + gg];
        }
#pragma unroll
        for (int i = 0; i < 2; ++i) {
            int idx = t + 256 * i;
            int gg = idx >> 4, e4 = idx & 15;
            *(float4*)&sWt[gg * 68 + e4 * 4] =
                *(const float4*)&wt[((size_t)k * G_ + gc * 32 + gg) * 64 + e4 * 4];
        }
        __syncthreads();
#pragma unroll 2
        for (int gg = 0; gg < 32; ++gg) {
            float4 x0 = *(const float4*)&imgT[gg * 132 + ti * 8];
            float4 x1 = *(const float4*)&imgT[gg * 132 + ti * 8 + 4];
            float4 yv = *(const float4*)&sWt[gg * 68 + tj * 4];
            float xs[8] = {x0.x, x0.y, x0.z, x0.w, x1.x, x1.y, x1.z, x1.w};
            float ys[4] = {yv.x, yv.y, yv.z, yv.w};
#pragma unroll
            for (int a = 0; a < 8; ++a)
#pragma unroll
                for (int b = 0; b < 4; ++b) acc[a][b] += xs[a] * ys[b];
        }
    }
    // epilogue: per-row sum over e of (T - vtilde)^2, reduce across tj lanes
    float4 vt = *(const float4*)&sVt[tj * 4];
#pragma unroll
    for (int a = 0; a < 8; ++a) {
        float d0 = acc[a][0] - vt.x;
        float d1 = acc[a][1] - vt.y;
        float d2 = acc[a][2] - vt.z;
        float d3 = acc[a][3] - vt.w;
        float s = d0 * d0 + d1 * d1 + d2 * d2 + d3 * d3;
        s += __shfl_xor(s, 1, 64);
        s += __shfl_xor(s, 2, 64);
        s += __shfl_xor(s, 4, 64);
        s += __shfl_xor(s, 8, 64);
        if (tj == 0) {
            size_t idx = (size_t)(b0 + ti * 8 + a) * K_ + k;
            ws[OFF_SC + idx] = ws[OFF_LIN + idx] - s;
        }
    }
}

// ---------------------------------------------------------------------------
// G2: per b: argmin_k score (first-index tie-break), then
//     u = W_k^T img - v ; z6 = Q6 u ; y = W_k z6 + m_k    (grid B, block 256)
__global__ __launch_bounds__(256) void g2_kernel(const float* __restrict__ img,
                                                 const float* __restrict__ mu,
                                                 const float* __restrict__ w,
                                                 const float* __restrict__ ws,
                                                 float* __restrict__ out) {
    const int b = blockIdx.x;
    const int t = threadIdx.x;
    __shared__ float rv[4];
    __shared__ int ri[4];
    __shared__ int skbest;
    __shared__ float simg[256];
    __shared__ float up[4][64];
    __shared__ float su[64];
    __shared__ float sz[64];

    float val = ws[OFF_SC + (size_t)b * K_ + t];
    int idx = t;
#pragma unroll
    for (int off = 32; off >= 1; off >>= 1) {
        float ov = __shfl_down(val, off, 64);
        int oi = __shfl_down(idx, off, 64);
        if (ov < val || (ov == val && oi < idx)) { val = ov; idx = oi; }
    }
    if ((t & 63) == 0) { rv[t >> 6] = val; ri[t >> 6] = idx; }
    simg[t] = img[(size_t)b * G_ + t];
    __syncthreads();
    if (t == 0) {
        float bv = rv[0]; int bi = ri[0];
#pragma unroll
        for (int i = 1; i < 4; ++i)
            if (rv[i] < bv || (rv[i] == bv && ri[i] < bi)) { bv = rv[i]; bi = ri[i]; }
        skbest = bi;
    }
    __syncthreads();
    const int kb = skbest;
    const int e = t & 63, p = t >> 6;

    {
        float acc = 0.f;
        const float* wcol = w + ((size_t)kb * G_ + p * 64) * E_ + e;
        for (int g = 0; g < 64; ++g) acc += wcol[(size_t)g * E_] * simg[p * 64 + g];
        up[p][e] = acc;
    }
    __syncthreads();
    if (t < 64)
        su[t] = up[0][t] + up[1][t] + up[2][t] + up[3][t] - ws[OFF_V + (size_t)kb * 64 + t];
    __syncthreads();
    {
        float acc = 0.f;
        const float* qrow = ws + OFF_Q6 + (size_t)kb * 4096 + e * 64 + p * 16;
#pragma unroll
        for (int f = 0; f < 16; ++f) acc += qrow[f] * su[p * 16 + f];
        up[p][e] = acc;
    }
    __syncthreads();
    if (t < 64) sz[t] = up[0][t] + up[1][t] + up[2][t] + up[3][t];
    __syncthreads();
    {
        float acc = 0.f;
        const float* wrow = w + ((size_t)kb * G_ + t) * E_;
#pragma unroll 8
        for (int e2 = 0; e2 < 64; ++e2) acc += wrow[e2] * sz[e2];
        out[(size_t)b * G_ + t] = acc + mu[(size_t)t * K_ + kb];
    }
}

// ---------------------------------------------------------------------------
static double binomd(int n, int r) {
    double v = 1.0;
    for (int i = 1; i <= r; ++i) v = v * (double)(n - r + i) / (double)i;
    return v;
}

extern "C" void kernel_launch(void* const* d_in, const int* in_sizes, int n_in,
                              void* d_out, int out_size, void* d_ws, size_t ws_size,
                              hipStream_t stream) {
    const float* img = (const float*)d_in[0];
    const float* mu  = (const float*)d_in[1];
    const float* w   = (const float*)d_in[2];
    float* out = (float*)d_out;
    float* ws = (float*)d_ws;

    double c5d[6], c6d[6];
    for (int j = 0; j < 6; ++j) { c5d[j] = 0.0; c6d[j] = 0.0; }
    const double a = 0.95, nb = -0.05;
    for (int i = 0; i <= 5; ++i) {
        for (int j = 0; j <= i; ++j) {
            double term = binomd(i, j) * pow(a, (double)(i - j)) * pow(nb, (double)j);
            c6d[j] += term;
            if (i <= 4) c5d[j] += term;
        }
    }
    CoefF cf;
    for (int j = 0; j < 6; ++j) { cf.c5[j] = (float)c5d[j]; cf.c6[j] = (float)c6d[j]; }

    hipLaunchKernelGGL(pre_kernel, dim3(K_), dim3(256), 0, stream, w, mu, ws, cf);
    hipLaunchKernelGGL(l1_kernel, dim3(16, 4), dim3(256), 0, stream, img, mu, ws);
    hipLaunchKernelGGL(g1_kernel, dim3(8, K_), dim3(256), 0, stream, img, ws);
    hipLaunchKernelGGL(g2_kernel, dim3(B_), dim3(256), 0, stream, img, mu, w, ws, out);
}

// Round 3
// 271.028 us; speedup vs baseline: 1.4278x; 1.4278x over previous
//
#include <hip/hip_runtime.h>
#include <math.h>

#define B_ 1024
#define G_ 256
#define K_ 256
#define E_ 64
#define D_CH 14   // max Chebyshev index
#define PX 68     // LDS pitch for 64-wide matrices (even, mult of 4)

// ws layout (in floats)
#define OFF_Q6  ((size_t)0)                          // K*E*E
#define OFF_V   ((size_t)(K_ * E_ * E_))             // K*E
#define OFF_VT  (OFF_V + (size_t)K_ * E_)            // K*E  (vtilde = F v)
#define OFF_MSQ (OFF_VT + (size_t)K_ * E_)           // K
#define OFF_LIN (OFF_MSQ + (size_t)K_)               // B*K
#define OFF_SC  (OFF_LIN + (size_t)B_ * K_)          // B*K
#define OFF_WT  (OFF_SC + (size_t)B_ * K_)           // K*G*E (Wtilde = W * F)

struct Cheb { float cF[D_CH + 1]; float cQ[D_CH + 1]; float alpha; float gamma; };

// ---------------------------------------------------------------------------
// pre: per k (grid K, block 512):
//   A = W^T W, v = W^T m, msq = ||m||^2
//   X = alpha*A + gamma*I (Chebyshev argument)
//   Chebyshev recurrence T_j(X): accumulate F = q(A) ~ sqrt(N), Q6 = beta*P6(A)
//   Wtilde = W*F ; vtilde = F*v
__global__ __launch_bounds__(512) void pre_kernel(const float* __restrict__ w,
                                                  const float* __restrict__ mu,
                                                  float* __restrict__ ws, Cheb cf) {
    const int k = blockIdx.x;
    const int t = threadIdx.x;
    const int ti = t >> 4;   // 0..31 -> rows ti*2, ti*2+1
    const int tj = t & 15;   // cols tj*4 .. tj*4+3
    const int r0 = ti * 2, c0 = tj * 4;
    __shared__ __align__(16) float sW[64 * PX];
    __shared__ __align__(16) float bufX[64 * PX];
    __shared__ __align__(16) float bufTa[64 * PX];
    __shared__ __align__(16) float bufTb[64 * PX];
    __shared__ float sV[64];
    __shared__ float sMu[64];
    __shared__ float dred[512];

    // ---- phase A: A = W^T W, v, msq ----
    float acc[2][4];
#pragma unroll
    for (int a = 0; a < 2; ++a)
#pragma unroll
        for (int b = 0; b < 4; ++b) acc[a][b] = 0.f;
    float vacc = 0.f, msqacc = 0.f;
    const int e_t = t & 63, p_t = t >> 6;  // p_t 0..7

    for (int gc = 0; gc < 4; ++gc) {
        __syncthreads();
#pragma unroll
        for (int i = 0; i < 2; ++i) {
            int idx = t + 512 * i;           // 1024 float4s
            int gg = idx >> 4, e4 = idx & 15;
            *(float4*)&sW[gg * PX + e4 * 4] =
                *(const float4*)&w[((size_t)k * G_ + gc * 64 + gg) * 64 + e4 * 4];
        }
        if (t < 64) sMu[t] = mu[(size_t)(gc * 64 + t) * K_ + k];
        __syncthreads();
#pragma unroll 4
        for (int gg = 0; gg < 64; ++gg) {
            float2 xa = *(const float2*)&sW[gg * PX + r0];
            float4 yb = *(const float4*)&sW[gg * PX + c0];
            acc[0][0] += xa.x * yb.x; acc[0][1] += xa.x * yb.y;
            acc[0][2] += xa.x * yb.z; acc[0][3] += xa.x * yb.w;
            acc[1][0] += xa.y * yb.x; acc[1][1] += xa.y * yb.y;
            acc[1][2] += xa.y * yb.z; acc[1][3] += xa.y * yb.w;
        }
        for (int gg = p_t * 8; gg < p_t * 8 + 8; ++gg)
            vacc += sW[gg * PX + e_t] * sMu[gg];
        if (t == 511) {
            for (int gg = 0; gg < 64; ++gg) msqacc += sMu[gg] * sMu[gg];
        }
    }
    __syncthreads();
    dred[t] = vacc;
    if (t == 511) ws[OFF_MSQ + k] = msqacc;
    __syncthreads();
    if (t < 64) {
        float v = 0.f;
#pragma unroll
        for (int j = 0; j < 8; ++j) v += dred[t + 64 * j];
        sV[t] = v;
        ws[OFF_V + (size_t)k * 64 + t] = v;
    }

    // X = alpha*A + gamma*I ; keep own tile in regs
    float xt[2][4];
#pragma unroll
    for (int a = 0; a < 2; ++a)
#pragma unroll
        for (int b = 0; b < 4; ++b) {
            int e = r0 + a, f = c0 + b;
            float xv = cf.alpha * acc[a][b] + ((e == f) ? cf.gamma : 0.f);
            xt[a][b] = xv;
            bufX[e * PX + f] = xv;
        }
    // init accumulators with T0=I, T1=X
    float Fa[2][4], Qa[2][4];
#pragma unroll
    for (int a = 0; a < 2; ++a)
#pragma unroll
        for (int b = 0; b < 4; ++b) {
            float id = (r0 + a == c0 + b) ? 1.f : 0.f;
            Fa[a][b] = cf.cF[0] * id + cf.cF[1] * xt[a][b];
            Qa[a][b] = cf.cQ[0] * id + cf.cQ[1] * xt[a][b];
        }
    __syncthreads();

    // T2 = 2*X*X - I
    {
        float gt[2][4];
#pragma unroll
        for (int a = 0; a < 2; ++a)
#pragma unroll
            for (int b = 0; b < 4; ++b) gt[a][b] = 0.f;
#pragma unroll 4
        for (int l = 0; l < 64; ++l) {
            float2 xa = *(const float2*)&bufX[l * PX + r0];
            float4 yb = *(const float4*)&bufX[l * PX + c0];
            gt[0][0] += xa.x * yb.x; gt[0][1] += xa.x * yb.y;
            gt[0][2] += xa.x * yb.z; gt[0][3] += xa.x * yb.w;
            gt[1][0] += xa.y * yb.x; gt[1][1] += xa.y * yb.y;
            gt[1][2] += xa.y * yb.z; gt[1][3] += xa.y * yb.w;
        }
#pragma unroll
        for (int a = 0; a < 2; ++a)
#pragma unroll
            for (int b = 0; b < 4; ++b) {
                float id = (r0 + a == c0 + b) ? 1.f : 0.f;
                float tn = 2.f * gt[a][b] - id;
                bufTa[(r0 + a) * PX + c0 + b] = tn;
                Fa[a][b] += cf.cF[2] * tn;
                Qa[a][b] += cf.cQ[2] * tn;
            }
        __syncthreads();
    }
    // T3 = 2*X*T2 - X
    {
        float gt[2][4];
#pragma unroll
        for (int a = 0; a < 2; ++a)
#pragma unroll
            for (int b = 0; b < 4; ++b) gt[a][b] = 0.f;
#pragma unroll 4
        for (int l = 0; l < 64; ++l) {
            float2 xa = *(const float2*)&bufX[l * PX + r0];
            float4 yb = *(const float4*)&bufTa[l * PX + c0];
            gt[0][0] += xa.x * yb.x; gt[0][1] += xa.x * yb.y;
            gt[0][2] += xa.x * yb.z; gt[0][3] += xa.x * yb.w;
            gt[1][0] += xa.y * yb.x; gt[1][1] += xa.y * yb.y;
            gt[1][2] += xa.y * yb.z; gt[1][3] += xa.y * yb.w;
        }
#pragma unroll
        for (int a = 0; a < 2; ++a)
#pragma unroll
            for (int b = 0; b < 4; ++b) {
                float tn = 2.f * gt[a][b] - xt[a][b];
                bufTb[(r0 + a) * PX + c0 + b] = tn;
                Fa[a][b] += cf.cF[3] * tn;
                Qa[a][b] += cf.cQ[3] * tn;
            }
        __syncthreads();
    }
    // generic steps j = 4..D_CH
    {
        float* cur = bufTb;
        float* old_ = bufTa;
        for (int j = 4; j <= D_CH; ++j) {
            float gt[2][4];
#pragma unroll
            for (int a = 0; a < 2; ++a)
#pragma unroll
                for (int b = 0; b < 4; ++b) gt[a][b] = 0.f;
#pragma unroll 4
            for (int l = 0; l < 64; ++l) {
                float2 xa = *(const float2*)&bufX[l * PX + r0];
                float4 yb = *(const float4*)&cur[l * PX + c0];
                gt[0][0] += xa.x * yb.x; gt[0][1] += xa.x * yb.y;
                gt[0][2] += xa.x * yb.z; gt[0][3] += xa.x * yb.w;
                gt[1][0] += xa.y * yb.x; gt[1][1] += xa.y * yb.y;
                gt[1][2] += xa.y * yb.z; gt[1][3] += xa.y * yb.w;
            }
            float cFj = cf.cF[j], cQj = cf.cQ[j];
#pragma unroll
            for (int a = 0; a < 2; ++a)
#pragma unroll
                for (int b = 0; b < 4; ++b) {
                    float oldv = old_[(r0 + a) * PX + c0 + b];  // own tile only
                    float tn = 2.f * gt[a][b] - oldv;
                    old_[(r0 + a) * PX + c0 + b] = tn;
                    Fa[a][b] += cFj * tn;
                    Qa[a][b] += cQj * tn;
                }
            __syncthreads();
            float* tmp = cur; cur = old_; old_ = tmp;
        }
    }
    // F -> bufX (X dead); Q6 -> global
#pragma unroll
    for (int a = 0; a < 2; ++a) {
        bufX[(r0 + a) * PX + c0 + 0] = Fa[a][0];
        bufX[(r0 + a) * PX + c0 + 1] = Fa[a][1];
        bufX[(r0 + a) * PX + c0 + 2] = Fa[a][2];
        bufX[(r0 + a) * PX + c0 + 3] = Fa[a][3];
        float4 q = make_float4(Qa[a][0], Qa[a][1], Qa[a][2], Qa[a][3]);
        *(float4*)&ws[OFF_Q6 + (size_t)k * 4096 + (r0 + a) * 64 + c0] = q;
    }
    __syncthreads();
    // vtilde = F v
    {
        float vt = 0.f;
        for (int f = p_t * 8; f < p_t * 8 + 8; ++f)
            vt += sV[f] * bufX[f * PX + e_t];
        dred[t] = vt;
        __syncthreads();
        if (t < 64) {
            float s = 0.f;
#pragma unroll
            for (int j = 0; j < 8; ++j) s += dred[t + 64 * j];
            ws[OFF_VT + (size_t)k * 64 + t] = s;
        }
    }
    // Wtilde = W * F
    for (int rc = 0; rc < 4; ++rc) {
        __syncthreads();
#pragma unroll
        for (int i = 0; i < 2; ++i) {
            int idx = t + 512 * i;
            int gg = idx >> 4, e4 = idx & 15;
            *(float4*)&sW[gg * PX + e4 * 4] =
                *(const float4*)&w[((size_t)k * G_ + rc * 64 + gg) * 64 + e4 * 4];
        }
        __syncthreads();
        float wt[2][4];
#pragma unroll
        for (int a = 0; a < 2; ++a)
#pragma unroll
            for (int b = 0; b < 4; ++b) wt[a][b] = 0.f;
#pragma unroll 4
        for (int l = 0; l < 64; ++l) {
            float x0 = sW[(r0 + 0) * PX + l];
            float x1 = sW[(r0 + 1) * PX + l];
            float4 yb = *(const float4*)&bufX[l * PX + c0];
            wt[0][0] += x0 * yb.x; wt[0][1] += x0 * yb.y;
            wt[0][2] += x0 * yb.z; wt[0][3] += x0 * yb.w;
            wt[1][0] += x1 * yb.x; wt[1][1] += x1 * yb.y;
            wt[1][2] += x1 * yb.z; wt[1][3] += x1 * yb.w;
        }
#pragma unroll
        for (int a = 0; a < 2; ++a) {
            float4 o = make_float4(wt[a][0], wt[a][1], wt[a][2], wt[a][3]);
            *(float4*)&ws[OFF_WT + ((size_t)k * G_ + rc * 64 + r0 + a) * 64 + c0] = o;
        }
    }
}

// ---------------------------------------------------------------------------
// L1: lin[b,k] = msq[k] - 2 * sum_g img[b,g]*mu[g,k]   (grid (32,8), block 256)
__global__ __launch_bounds__(256) void l1_kernel(const float* __restrict__ img,
                                                 const float* __restrict__ mu,
                                                 float* __restrict__ ws) {
    const int b0 = blockIdx.x * 32;
    const int k0 = blockIdx.y * 32;
    const int t = threadIdx.x;
    const int ti = t >> 4, tj = t & 15;   // 2x2 tiles
    __shared__ float sI[32 * 34];  // [g][b]
    __shared__ float sM[32 * 34];  // [g][k]
    float acc[2][2] = {{0.f, 0.f}, {0.f, 0.f}};

    const int cc = t & 31, rr = t >> 5;  // staging
    for (int gc = 0; gc < 8; ++gc) {
        __syncthreads();
#pragma unroll
        for (int i = 0; i < 4; ++i) {
            int r = rr + 8 * i;
            sI[cc * 34 + r] = img[(size_t)(b0 + r) * G_ + gc * 32 + cc];
            sM[r * 34 + cc] = mu[(size_t)(gc * 32 + r) * K_ + k0 + cc];
        }
        __syncthreads();
#pragma unroll 4
        for (int gg = 0; gg < 32; ++gg) {
            float2 xa = *(const float2*)&sI[gg * 34 + ti * 2];
            float2 yb = *(const float2*)&sM[gg * 34 + tj * 2];
            acc[0][0] += xa.x * yb.x; acc[0][1] += xa.x * yb.y;
            acc[1][0] += xa.y * yb.x; acc[1][1] += xa.y * yb.y;
        }
    }
#pragma unroll
    for (int a = 0; a < 2; ++a)
#pragma unroll
        for (int b = 0; b < 2; ++b) {
            int kk = k0 + tj * 2 + b;
            ws[OFF_LIN + (size_t)(b0 + ti * 2 + a) * K_ + kk] =
                ws[OFF_MSQ + kk] - 2.0f * acc[a][b];
        }
}

// ---------------------------------------------------------------------------
// G1: per (k, 128-row b tile): T = img * Wtilde_k ;
//     score[b,k] = lin[b,k] - sum_e (T[b,e] - vtilde[e])^2
// grid (8, K), block 256
__global__ __launch_bounds__(256) void g1_kernel(const float* __restrict__ img,
                                                 float* __restrict__ ws) {
    const int k = blockIdx.y;
    const int b0 = blockIdx.x * 128;
    const int t = threadIdx.x;
    const int ti = t >> 4, tj = t & 15;
    __shared__ __align__(16) float imgT[32 * 132];
    __shared__ __align__(16) float sWt[32 * 68];
    __shared__ float sVt[64];
    const float* wt = ws + OFF_WT;

    if (t < 64) sVt[t] = ws[OFF_VT + (size_t)k * 64 + t];

    float acc[8][4];
#pragma unroll
    for (int a = 0; a < 8; ++a)
#pragma unroll
        for (int b = 0; b < 4; ++b) acc[a][b] = 0.f;

    for (int gc = 0; gc < 8; ++gc) {
        __syncthreads();
#pragma unroll
        for (int i = 0; i < 16; ++i) {
            int lin = t + 256 * i;
            int r = lin >> 5, gg = lin & 31;
            imgT[gg * 132 + r] = img[(size_t)(b0 + r) * G_ + gc * 32 + gg];
        }
#pragma unroll
        for (int i = 0; i < 2; ++i) {
            int idx = t + 256 * i;
            int gg = idx >> 4, e4 = idx & 15;
            *(float4*)&sWt[gg * 68 + e4 * 4] =
                *(const float4*)&wt[((size_t)k * G_ + gc * 32 + gg) * 64 + e4 * 4];
        }
        __syncthreads();
#pragma unroll 2
        for (int gg = 0; gg < 32; ++gg) {
            float4 x0 = *(const float4*)&imgT[gg * 132 + ti * 8];
            float4 x1 = *(const float4*)&imgT[gg * 132 + ti * 8 + 4];
            float4 yv = *(const float4*)&sWt[gg * 68 + tj * 4];
            float xs[8] = {x0.x, x0.y, x0.z, x0.w, x1.x, x1.y, x1.z, x1.w};
            float ys[4] = {yv.x, yv.y, yv.z, yv.w};
#pragma unroll
            for (int a = 0; a < 8; ++a)
#pragma unroll
                for (int b = 0; b < 4; ++b) acc[a][b] += xs[a] * ys[b];
        }
    }
    float4 vt = *(const float4*)&sVt[tj * 4];
#pragma unroll
    for (int a = 0; a < 8; ++a) {
        float d0 = acc[a][0] - vt.x;
        float d1 = acc[a][1] - vt.y;
        float d2 = acc[a][2] - vt.z;
        float d3 = acc[a][3] - vt.w;
        float s = d0 * d0 + d1 * d1 + d2 * d2 + d3 * d3;
        s += __shfl_xor(s, 1, 64);
        s += __shfl_xor(s, 2, 64);
        s += __shfl_xor(s, 4, 64);
        s += __shfl_xor(s, 8, 64);
        if (tj == 0) {
            size_t idx = (size_t)(b0 + ti * 8 + a) * K_ + k;
            ws[OFF_SC + idx] = ws[OFF_LIN + idx] - s;
        }
    }
}

// ---------------------------------------------------------------------------
// G2: per b: argmin_k score (first-index tie-break), then
//     u = W_k^T img - v ; z6 = Q6 u ; y = W_k z6 + m_k    (grid B, block 256)
__global__ __launch_bounds__(256) void g2_kernel(const float* __restrict__ img,
                                                 const float* __restrict__ mu,
                                                 const float* __restrict__ w,
                                                 const float* __restrict__ ws,
                                                 float* __restrict__ out) {
    const int b = blockIdx.x;
    const int t = threadIdx.x;
    __shared__ float rv[4];
    __shared__ int ri[4];
    __shared__ int skbest;
    __shared__ float simg[256];
    __shared__ float up[4][64];
    __shared__ float su[64];
    __shared__ float sz[64];

    float val = ws[OFF_SC + (size_t)b * K_ + t];
    int idx = t;
#pragma unroll
    for (int off = 32; off >= 1; off >>= 1) {
        float ov = __shfl_down(val, off, 64);
        int oi = __shfl_down(idx, off, 64);
        if (ov < val || (ov == val && oi < idx)) { val = ov; idx = oi; }
    }
    if ((t & 63) == 0) { rv[t >> 6] = val; ri[t >> 6] = idx; }
    simg[t] = img[(size_t)b * G_ + t];
    __syncthreads();
    if (t == 0) {
        float bv = rv[0]; int bi = ri[0];
#pragma unroll
        for (int i = 1; i < 4; ++i)
            if (rv[i] < bv || (rv[i] == bv && ri[i] < bi)) { bv = rv[i]; bi = ri[i]; }
        skbest = bi;
    }
    __syncthreads();
    const int kb = skbest;
    const int e = t & 63, p = t >> 6;

    {
        float acc = 0.f;
        const float* wcol = w + ((size_t)kb * G_ + p * 64) * E_ + e;
        for (int g = 0; g < 64; ++g) acc += wcol[(size_t)g * E_] * simg[p * 64 + g];
        up[p][e] = acc;
    }
    __syncthreads();
    if (t < 64)
        su[t] = up[0][t] + up[1][t] + up[2][t] + up[3][t] - ws[OFF_V + (size_t)kb * 64 + t];
    __syncthreads();
    {
        float acc = 0.f;
        const float* qrow = ws + OFF_Q6 + (size_t)kb * 4096 + e * 64 + p * 16;
#pragma unroll
        for (int f = 0; f < 16; ++f) acc += qrow[f] * su[p * 16 + f];
        up[p][e] = acc;
    }
    __syncthreads();
    if (t < 64) sz[t] = up[0][t] + up[1][t] + up[2][t] + up[3][t];
    __syncthreads();
    {
        float acc = 0.f;
        const float* wrow = w + ((size_t)kb * G_ + t) * E_;
#pragma unroll 8
        for (int e2 = 0; e2 < 64; ++e2) acc += wrow[e2] * sz[e2];
        out[(size_t)b * G_ + t] = acc + mu[(size_t)t * K_ + kb];
    }
}

// ---------------------------------------------------------------------------
extern "C" void kernel_launch(void* const* d_in, const int* in_sizes, int n_in,
                              void* d_out, int out_size, void* d_ws, size_t ws_size,
                              hipStream_t stream) {
    const float* img = (const float*)d_in[0];
    const float* mu  = (const float*)d_in[1];
    const float* w   = (const float*)d_in[2];
    float* out = (float*)d_out;
    float* ws = (float*)d_ws;

    // Chebyshev fits on lambda in [aa,bb]:
    //   fF(l) = sqrt(2b*p5 - b^2*l*p5^2), fQ(l) = b*p6,  b=0.05
    const double aa = 0.06, bb = 1.85;
    const int NN = 64;
    double fF[NN], fQ[NN];
    for (int i = 0; i < NN; ++i) {
        double x = cos(M_PI * (i + 0.5) / NN);
        double lam = 0.5 * (aa + bb) + 0.5 * (bb - aa) * x;
        double m = 0.95 - 0.05 * lam;
        double p5 = 0.0, pw = 1.0;
        for (int j = 0; j < 5; ++j) { p5 += pw; pw *= m; }
        double p6 = p5 + pw;
        double p = 2.0 * 0.05 * p5 - 0.05 * 0.05 * lam * p5 * p5;
        fF[i] = sqrt(p);
        fQ[i] = 0.05 * p6;
    }
    Cheb cf;
    for (int j = 0; j <= D_CH; ++j) {
        double sF = 0.0, sQ = 0.0;
        for (int i = 0; i < NN; ++i) {
            double cw = cos(M_PI * j * (i + 0.5) / NN);
            sF += fF[i] * cw;
            sQ += fQ[i] * cw;
        }
        double sc = 2.0 / NN;
        if (j == 0) sc *= 0.5;
        cf.cF[j] = (float)(sF * sc);
        cf.cQ[j] = (float)(sQ * sc);
    }
    cf.alpha = (float)(2.0 / (bb - aa));
    cf.gamma = (float)(-(bb + aa) / (bb - aa));

    hipLaunchKernelGGL(pre_kernel, dim3(K_), dim3(512), 0, stream, w, mu, ws, cf);
    hipLaunchKernelGGL(l1_kernel, dim3(32, 8), dim3(256), 0, stream, img, mu, ws);
    hipLaunchKernelGGL(g1_kernel, dim3(8, K_), dim3(256), 0, stream, img, ws);
    hipLaunchKernelGGL(g2_kernel, dim3(B_), dim3(256), 0, stream, img, mu, w, ws, out);
}

// Round 4
// 189.695 us; speedup vs baseline: 2.0400x; 1.4288x over previous
//
#include <hip/hip_runtime.h>
#include <math.h>

#define B_ 1024
#define G_ 256
#define K_ 256
#define E_ 64
#define D_CH 14   // max Chebyshev index
#define PX 68     // LDS pitch for 64-wide fp32 matrices (even, mult of 4)
#define LP 40     // LDS pitch (ushorts) for 32-g bf16 chunks: 80B stride, 16B-aligned, 2-way max

// ws layout (floats)
#define OFF_Q6  ((size_t)0)                          // K*E*E = 1048576
#define OFF_V   ((size_t)1048576)                    // K*E   = 16384
#define OFF_VT  ((size_t)1064960)                    // K*E   = 16384
#define OFF_MSQ ((size_t)1081344)                    // K     = 256
#define OFF_SC  ((size_t)1081600)                    // B*K   = 262144
#define OFF_U16 ((size_t)1343744)                    // ushort area starts here (16B aligned)
// ushort offsets within (ushort*)(ws + OFF_U16)
#define U_WTH  ((size_t)0)           // K*80*256 = 5242880
#define U_WTL  ((size_t)5242880)
#define U_IMGH ((size_t)10485760)    // B*G = 262144
#define U_IMGL ((size_t)10747904)

typedef short v8s __attribute__((ext_vector_type(8)));
typedef float v4f __attribute__((ext_vector_type(4)));

struct Cheb { float cF[D_CH + 1]; float cQ[D_CH + 1]; float alpha; float gamma; };

__device__ __forceinline__ unsigned short bf16_rne(float x) {
    unsigned int u = __float_as_uint(x);
    unsigned int r = (u + 0x7FFFu + ((u >> 16) & 1u)) >> 16;
    return (unsigned short)r;
}
__device__ __forceinline__ float bf16_to_f(unsigned short h) {
    return __uint_as_float(((unsigned int)h) << 16);
}

// ---------------------------------------------------------------------------
// split: imgH/imgL bf16 hi/lo of img. grid 256, block 256, 4 floats/thread.
__global__ __launch_bounds__(256) void split_kernel(const float* __restrict__ img,
                                                    float* __restrict__ ws) {
    unsigned short* wsu = (unsigned short*)(ws + OFF_U16);
    unsigned short* imgH = wsu + U_IMGH;
    unsigned short* imgL = wsu + U_IMGL;
    int i = blockIdx.x * 256 + threadIdx.x;     // 65536 float4s
    float4 x = ((const float4*)img)[i];
    ushort4 h, l;
    h.x = bf16_rne(x.x); l.x = bf16_rne(x.x - bf16_to_f(h.x));
    h.y = bf16_rne(x.y); l.y = bf16_rne(x.y - bf16_to_f(h.y));
    h.z = bf16_rne(x.z); l.z = bf16_rne(x.z - bf16_to_f(h.z));
    h.w = bf16_rne(x.w); l.w = bf16_rne(x.w - bf16_to_f(h.w));
    ((ushort4*)imgH)[i] = h;
    ((ushort4*)imgL)[i] = l;
}

// ---------------------------------------------------------------------------
// pre: per k (grid K, block 512):
//   A = W^T W, v = W^T m, msq = ||m||^2
//   Chebyshev recurrence: F = q(A) ~ sqrt(N), Q6 = beta*P6(A)
//   vtilde = F v ; wtT[k][e][g] = (W F)^T as bf16 hi/lo ; col 64 = mu_k hi/lo
__global__ __launch_bounds__(512) void pre_kernel(const float* __restrict__ w,
                                                  const float* __restrict__ mu,
                                                  float* __restrict__ ws, Cheb cf) {
    const int k = blockIdx.x;
    const int t = threadIdx.x;
    const int ti = t >> 4;
    const int tj = t & 15;
    const int r0 = ti * 2, c0 = tj * 4;
    __shared__ __align__(16) float sW[64 * PX];
    __shared__ __align__(16) float bufX[64 * PX];
    __shared__ __align__(16) float bufTa[64 * PX];
    __shared__ __align__(16) float bufTb[64 * PX];
    __shared__ float sV[64];
    __shared__ float sMu[64];
    __shared__ float dred[512];

    unsigned short* wsu = (unsigned short*)(ws + OFF_U16);
    unsigned short* wtTH = wsu + U_WTH;
    unsigned short* wtTL = wsu + U_WTL;

    // ---- phase A: A = W^T W, v, msq ----
    float acc[2][4];
#pragma unroll
    for (int a = 0; a < 2; ++a)
#pragma unroll
        for (int b = 0; b < 4; ++b) acc[a][b] = 0.f;
    float vacc = 0.f, msqacc = 0.f;
    const int e_t = t & 63, p_t = t >> 6;

    for (int gc = 0; gc < 4; ++gc) {
        __syncthreads();
#pragma unroll
        for (int i = 0; i < 2; ++i) {
            int idx = t + 512 * i;
            int gg = idx >> 4, e4 = idx & 15;
            *(float4*)&sW[gg * PX + e4 * 4] =
                *(const float4*)&w[((size_t)k * G_ + gc * 64 + gg) * 64 + e4 * 4];
        }
        if (t < 64) sMu[t] = mu[(size_t)(gc * 64 + t) * K_ + k];
        __syncthreads();
#pragma unroll 4
        for (int gg = 0; gg < 64; ++gg) {
            float2 xa = *(const float2*)&sW[gg * PX + r0];
            float4 yb = *(const float4*)&sW[gg * PX + c0];
            acc[0][0] += xa.x * yb.x; acc[0][1] += xa.x * yb.y;
            acc[0][2] += xa.x * yb.z; acc[0][3] += xa.x * yb.w;
            acc[1][0] += xa.y * yb.x; acc[1][1] += xa.y * yb.y;
            acc[1][2] += xa.y * yb.z; acc[1][3] += xa.y * yb.w;
        }
        for (int gg = p_t * 8; gg < p_t * 8 + 8; ++gg)
            vacc += sW[gg * PX + e_t] * sMu[gg];
        if (t == 511) {
            for (int gg = 0; gg < 64; ++gg) msqacc += sMu[gg] * sMu[gg];
        }
        // mu column -> wtT col 64 (hi/lo), while sMu holds this chunk
        if (t < 64) {
            unsigned short h = bf16_rne(sMu[t]);
            unsigned short l = bf16_rne(sMu[t] - bf16_to_f(h));
            size_t gcol = ((size_t)k * 80 + 64) * 256 + gc * 64 + t;
            wtTH[gcol] = h;
            wtTL[gcol] = l;
        }
    }
    __syncthreads();
    dred[t] = vacc;
    if (t == 511) ws[OFF_MSQ + k] = msqacc;
    __syncthreads();
    if (t < 64) {
        float v = 0.f;
#pragma unroll
        for (int j = 0; j < 8; ++j) v += dred[t + 64 * j];
        sV[t] = v;
        ws[OFF_V + (size_t)k * 64 + t] = v;
    }

    // X = alpha*A + gamma*I
    float xt[2][4];
#pragma unroll
    for (int a = 0; a < 2; ++a)
#pragma unroll
        for (int b = 0; b < 4; ++b) {
            int e = r0 + a, f = c0 + b;
            float xv = cf.alpha * acc[a][b] + ((e == f) ? cf.gamma : 0.f);
            xt[a][b] = xv;
            bufX[e * PX + f] = xv;
        }
    float Fa[2][4], Qa[2][4];
#pragma unroll
    for (int a = 0; a < 2; ++a)
#pragma unroll
        for (int b = 0; b < 4; ++b) {
            float id = (r0 + a == c0 + b) ? 1.f : 0.f;
            Fa[a][b] = cf.cF[0] * id + cf.cF[1] * xt[a][b];
            Qa[a][b] = cf.cQ[0] * id + cf.cQ[1] * xt[a][b];
        }
    __syncthreads();

    // T2 = 2*X*X - I
    {
        float gt[2][4];
#pragma unroll
        for (int a = 0; a < 2; ++a)
#pragma unroll
            for (int b = 0; b < 4; ++b) gt[a][b] = 0.f;
#pragma unroll 4
        for (int l = 0; l < 64; ++l) {
            float2 xa = *(const float2*)&bufX[l * PX + r0];
            float4 yb = *(const float4*)&bufX[l * PX + c0];
            gt[0][0] += xa.x * yb.x; gt[0][1] += xa.x * yb.y;
            gt[0][2] += xa.x * yb.z; gt[0][3] += xa.x * yb.w;
            gt[1][0] += xa.y * yb.x; gt[1][1] += xa.y * yb.y;
            gt[1][2] += xa.y * yb.z; gt[1][3] += xa.y * yb.w;
        }
#pragma unroll
        for (int a = 0; a < 2; ++a)
#pragma unroll
            for (int b = 0; b < 4; ++b) {
                float id = (r0 + a == c0 + b) ? 1.f : 0.f;
                float tn = 2.f * gt[a][b] - id;
                bufTa[(r0 + a) * PX + c0 + b] = tn;
                Fa[a][b] += cf.cF[2] * tn;
                Qa[a][b] += cf.cQ[2] * tn;
            }
        __syncthreads();
    }
    // T3 = 2*X*T2 - X
    {
        float gt[2][4];
#pragma unroll
        for (int a = 0; a < 2; ++a)
#pragma unroll
            for (int b = 0; b < 4; ++b) gt[a][b] = 0.f;
#pragma unroll 4
        for (int l = 0; l < 64; ++l) {
            float2 xa = *(const float2*)&bufX[l * PX + r0];
            float4 yb = *(const float4*)&bufTa[l * PX + c0];
            gt[0][0] += xa.x * yb.x; gt[0][1] += xa.x * yb.y;
            gt[0][2] += xa.x * yb.z; gt[0][3] += xa.x * yb.w;
            gt[1][0] += xa.y * yb.x; gt[1][1] += xa.y * yb.y;
            gt[1][2] += xa.y * yb.z; gt[1][3] += xa.y * yb.w;
        }
#pragma unroll
        for (int a = 0; a < 2; ++a)
#pragma unroll
            for (int b = 0; b < 4; ++b) {
                float tn = 2.f * gt[a][b] - xt[a][b];
                bufTb[(r0 + a) * PX + c0 + b] = tn;
                Fa[a][b] += cf.cF[3] * tn;
                Qa[a][b] += cf.cQ[3] * tn;
            }
        __syncthreads();
    }
    // generic steps j = 4..D_CH
    {
        float* cur = bufTb;
        float* old_ = bufTa;
        for (int j = 4; j <= D_CH; ++j) {
            float gt[2][4];
#pragma unroll
            for (int a = 0; a < 2; ++a)
#pragma unroll
                for (int b = 0; b < 4; ++b) gt[a][b] = 0.f;
#pragma unroll 4
            for (int l = 0; l < 64; ++l) {
                float2 xa = *(const float2*)&bufX[l * PX + r0];
                float4 yb = *(const float4*)&cur[l * PX + c0];
                gt[0][0] += xa.x * yb.x; gt[0][1] += xa.x * yb.y;
                gt[0][2] += xa.x * yb.z; gt[0][3] += xa.x * yb.w;
                gt[1][0] += xa.y * yb.x; gt[1][1] += xa.y * yb.y;
                gt[1][2] += xa.y * yb.z; gt[1][3] += xa.y * yb.w;
            }
            float cFj = cf.cF[j], cQj = cf.cQ[j];
#pragma unroll
            for (int a = 0; a < 2; ++a)
#pragma unroll
                for (int b = 0; b < 4; ++b) {
                    float oldv = old_[(r0 + a) * PX + c0 + b];
                    float tn = 2.f * gt[a][b] - oldv;
                    old_[(r0 + a) * PX + c0 + b] = tn;
                    Fa[a][b] += cFj * tn;
                    Qa[a][b] += cQj * tn;
                }
            __syncthreads();
            float* tmp = cur; cur = old_; old_ = tmp;
        }
    }
    // F -> bufX ; Q6 -> global
#pragma unroll
    for (int a = 0; a < 2; ++a) {
        bufX[(r0 + a) * PX + c0 + 0] = Fa[a][0];
        bufX[(r0 + a) * PX + c0 + 1] = Fa[a][1];
        bufX[(r0 + a) * PX + c0 + 2] = Fa[a][2];
        bufX[(r0 + a) * PX + c0 + 3] = Fa[a][3];
        float4 q = make_float4(Qa[a][0], Qa[a][1], Qa[a][2], Qa[a][3]);
        *(float4*)&ws[OFF_Q6 + (size_t)k * 4096 + (r0 + a) * 64 + c0] = q;
    }
    __syncthreads();
    // vtilde = F v
    {
        float vt = 0.f;
        for (int f = p_t * 8; f < p_t * 8 + 8; ++f)
            vt += sV[f] * bufX[f * PX + e_t];
        dred[t] = vt;
        __syncthreads();
        if (t < 64) {
            float s = 0.f;
#pragma unroll
            for (int j = 0; j < 8; ++j) s += dred[t + 64 * j];
            ws[OFF_VT + (size_t)k * 64 + t] = s;
        }
    }
    // Wtilde = W * F, write transposed bf16 hi/lo: wtT[k][e][g]
    unsigned short* TtH = (unsigned short*)bufTa;  // [64][72]
    unsigned short* TtL = (unsigned short*)bufTb;
    for (int rc = 0; rc < 4; ++rc) {
        __syncthreads();
#pragma unroll
        for (int i = 0; i < 2; ++i) {
            int idx = t + 512 * i;
            int gg = idx >> 4, e4 = idx & 15;
            *(float4*)&sW[gg * PX + e4 * 4] =
                *(const float4*)&w[((size_t)k * G_ + rc * 64 + gg) * 64 + e4 * 4];
        }
        __syncthreads();
        float wt[2][4];
#pragma unroll
        for (int a = 0; a < 2; ++a)
#pragma unroll
            for (int b = 0; b < 4; ++b) wt[a][b] = 0.f;
#pragma unroll 4
        for (int l = 0; l < 64; ++l) {
            float x0 = sW[(r0 + 0) * PX + l];
            float x1 = sW[(r0 + 1) * PX + l];
            float4 yb = *(const float4*)&bufX[l * PX + c0];
            wt[0][0] += x0 * yb.x; wt[0][1] += x0 * yb.y;
            wt[0][2] += x0 * yb.z; wt[0][3] += x0 * yb.w;
            wt[1][0] += x1 * yb.x; wt[1][1] += x1 * yb.y;
            wt[1][2] += x1 * yb.z; wt[1][3] += x1 * yb.w;
        }
        // transpose into ushort LDS tiles: Tt[e][g_local]
#pragma unroll
        for (int a = 0; a < 2; ++a)
#pragma unroll
            for (int b = 0; b < 4; ++b) {
                unsigned short h = bf16_rne(wt[a][b]);
                unsigned short l = bf16_rne(wt[a][b] - bf16_to_f(h));
                TtH[(c0 + b) * 72 + r0 + a] = h;
                TtL[(c0 + b) * 72 + r0 + a] = l;
            }
        __syncthreads();
        // dump: 64 e-rows x 64 g = 8 x 16B per row
        {
            int e = t >> 3, seg = t & 7;
            size_t gbase = ((size_t)k * 80 + e) * 256 + rc * 64 + seg * 8;
            *(uint4*)&wtTH[gbase] = *(const uint4*)&TtH[e * 72 + seg * 8];
            *(uint4*)&wtTL[gbase] = *(const uint4*)&TtL[e * 72 + seg * 8];
        }
    }
}

// ---------------------------------------------------------------------------
// G1: per (b-tile 128, k): T = img * [Wtilde | mu] via bf16 hi/lo 3-MFMA;
//     score[b,k] = msq[k] - 2*T[:,64] - sum_e (T[:,e] - vtilde[e])^2
// grid (8, K), block 256 (4 waves)
__global__ __launch_bounds__(256) void g1_kernel(float* __restrict__ ws) {
    const int k = blockIdx.y;
    const int b0 = blockIdx.x * 128;
    const int t = threadIdx.x;
    const int wid = t >> 6, lane = t & 63;
    const int c = lane & 15, q = lane >> 4;
    __shared__ __align__(16) unsigned short sIH[128 * LP];
    __shared__ __align__(16) unsigned short sIL[128 * LP];
    __shared__ __align__(16) unsigned short sWH[80 * LP];
    __shared__ __align__(16) unsigned short sWL[80 * LP];

    const unsigned short* wsu = (const unsigned short*)(ws + OFF_U16);
    const unsigned short* wtTH = wsu + U_WTH;
    const unsigned short* wtTL = wsu + U_WTL;
    const unsigned short* imgH = wsu + U_IMGH;
    const unsigned short* imgL = wsu + U_IMGL;

    v4f acc[2][5];
#pragma unroll
    for (int mt = 0; mt < 2; ++mt)
#pragma unroll
        for (int nt = 0; nt < 5; ++nt) acc[mt][nt] = (v4f){0.f, 0.f, 0.f, 0.f};

    for (int gc = 0; gc < 8; ++gc) {
        __syncthreads();
        // img staging: 128 rows x 32 g = 512 x16B (hi & lo)
#pragma unroll
        for (int i = 0; i < 2; ++i) {
            int idx = t + 256 * i;
            int r = idx >> 2, seg = idx & 3;
            size_t gsrc = (size_t)(b0 + r) * 256 + gc * 32 + seg * 8;
            *(uint4*)&sIH[r * LP + seg * 8] = *(const uint4*)&imgH[gsrc];
            *(uint4*)&sIL[r * LP + seg * 8] = *(const uint4*)&imgL[gsrc];
        }
        // wt staging: 80 cols x 32 g = 320 x16B
        {
            int col = t >> 2, seg = t & 3;
            size_t gsrc = ((size_t)k * 80 + col) * 256 + gc * 32 + seg * 8;
            *(uint4*)&sWH[col * LP + seg * 8] = *(const uint4*)&wtTH[gsrc];
            *(uint4*)&sWL[col * LP + seg * 8] = *(const uint4*)&wtTL[gsrc];
            if (t < 64) {
                int idx = t + 256;
                int col2 = idx >> 2, seg2 = idx & 3;
                size_t g2 = ((size_t)k * 80 + col2) * 256 + gc * 32 + seg2 * 8;
                *(uint4*)&sWH[col2 * LP + seg2 * 8] = *(const uint4*)&wtTH[g2];
                *(uint4*)&sWL[col2 * LP + seg2 * 8] = *(const uint4*)&wtTL[g2];
            }
        }
        __syncthreads();
        // A fragments (per wave: rows wid*32 + mt*16 + c)
        v8s aH[2], aL[2];
#pragma unroll
        for (int mt = 0; mt < 2; ++mt) {
            int row = wid * 32 + mt * 16 + c;
            aH[mt] = *(const v8s*)&sIH[row * LP + q * 8];
            aL[mt] = *(const v8s*)&sIL[row * LP + q * 8];
        }
#pragma unroll
        for (int nt = 0; nt < 5; ++nt) {
            int colr = nt * 16 + c;
            v8s bH = *(const v8s*)&sWH[colr * LP + q * 8];
            v8s bL = *(const v8s*)&sWL[colr * LP + q * 8];
#pragma unroll
            for (int mt = 0; mt < 2; ++mt) {
                acc[mt][nt] = __builtin_amdgcn_mfma_f32_16x16x32_bf16(aH[mt], bH, acc[mt][nt], 0, 0, 0);
                acc[mt][nt] = __builtin_amdgcn_mfma_f32_16x16x32_bf16(aH[mt], bL, acc[mt][nt], 0, 0, 0);
                acc[mt][nt] = __builtin_amdgcn_mfma_f32_16x16x32_bf16(aL[mt], bH, acc[mt][nt], 0, 0, 0);
            }
        }
    }
    // epilogue: C layout col=lane&15, row=q*4+r
    float msq = ws[OFF_MSQ + k];
    float vtr[4];
#pragma unroll
    for (int nt = 0; nt < 4; ++nt)
        vtr[nt] = ws[OFF_VT + (size_t)k * 64 + nt * 16 + c];
#pragma unroll
    for (int mt = 0; mt < 2; ++mt) {
        float tot[4];
#pragma unroll
        for (int r = 0; r < 4; ++r) tot[r] = 0.f;
#pragma unroll
        for (int nt = 0; nt < 4; ++nt)
#pragma unroll
            for (int r = 0; r < 4; ++r) {
                float d = acc[mt][nt][r] - vtr[nt];
                tot[r] += d * d;
            }
        if (c == 0) {
#pragma unroll
            for (int r = 0; r < 4; ++r) tot[r] += 2.f * acc[mt][4][r];
        }
#pragma unroll
        for (int r = 0; r < 4; ++r) {
            tot[r] += __shfl_xor(tot[r], 1, 64);
            tot[r] += __shfl_xor(tot[r], 2, 64);
            tot[r] += __shfl_xor(tot[r], 4, 64);
            tot[r] += __shfl_xor(tot[r], 8, 64);
        }
        if (c == 0) {
#pragma unroll
            for (int r = 0; r < 4; ++r) {
                int row = b0 + wid * 32 + mt * 16 + q * 4 + r;
                ws[OFF_SC + (size_t)row * K_ + k] = msq - tot[r];
            }
        }
    }
}

// ---------------------------------------------------------------------------
// G2: per b: argmin_k score (first-index tie-break), then
//     u = W_k^T img - v ; z6 = Q6 u ; y = W_k z6 + m_k    (grid B, block 256)
__global__ __launch_bounds__(256) void g2_kernel(const float* __restrict__ img,
                                                 const float* __restrict__ mu,
                                                 const float* __restrict__ w,
                                                 const float* __restrict__ ws,
                                                 float* __restrict__ out) {
    const int b = blockIdx.x;
    const int t = threadIdx.x;
    __shared__ float rv[4];
    __shared__ int ri[4];
    __shared__ int skbest;
    __shared__ float simg[256];
    __shared__ float up[4][64];
    __shared__ float su[64];
    __shared__ float sz[64];

    float val = ws[OFF_SC + (size_t)b * K_ + t];
    int idx = t;
#pragma unroll
    for (int off = 32; off >= 1; off >>= 1) {
        float ov = __shfl_down(val, off, 64);
        int oi = __shfl_down(idx, off, 64);
        if (ov < val || (ov == val && oi < idx)) { val = ov; idx = oi; }
    }
    if ((t & 63) == 0) { rv[t >> 6] = val; ri[t >> 6] = idx; }
    simg[t] = img[(size_t)b * G_ + t];
    __syncthreads();
    if (t == 0) {
        float bv = rv[0]; int bi = ri[0];
#pragma unroll
        for (int i = 1; i < 4; ++i)
            if (rv[i] < bv || (rv[i] == bv && ri[i] < bi)) { bv = rv[i]; bi = ri[i]; }
        skbest = bi;
    }
    __syncthreads();
    const int kb = skbest;
    const int e = t & 63, p = t >> 6;

    {
        float acc = 0.f;
        const float* wcol = w + ((size_t)kb * G_ + p * 64) * E_ + e;
        for (int g = 0; g < 64; ++g) acc += wcol[(size_t)g * E_] * simg[p * 64 + g];
        up[p][e] = acc;
    }
    __syncthreads();
    if (t < 64)
        su[t] = up[0][t] + up[1][t] + up[2][t] + up[3][t] - ws[OFF_V + (size_t)kb * 64 + t];
    __syncthreads();
    {
        float acc = 0.f;
        const float* qrow = ws + OFF_Q6 + (size_t)kb * 4096 + e * 64 + p * 16;
#pragma unroll
        for (int f = 0; f < 16; ++f) acc += qrow[f] * su[p * 16 + f];
        up[p][e] = acc;
    }
    __syncthreads();
    if (t < 64) sz[t] = up[0][t] + up[1][t] + up[2][t] + up[3][t];
    __syncthreads();
    {
        float acc = 0.f;
        const float* wrow = w + ((size_t)kb * G_ + t) * E_;
#pragma unroll 8
        for (int e2 = 0; e2 < 64; ++e2) acc += wrow[e2] * sz[e2];
        out[(size_t)b * G_ + t] = acc + mu[(size_t)t * K_ + kb];
    }
}

// ---------------------------------------------------------------------------
extern "C" void kernel_launch(void* const* d_in, const int* in_sizes, int n_in,
                              void* d_out, int out_size, void* d_ws, size_t ws_size,
                              hipStream_t stream) {
    const float* img = (const float*)d_in[0];
    const float* mu  = (const float*)d_in[1];
    const float* w   = (const float*)d_in[2];
    float* out = (float*)d_out;
    float* ws = (float*)d_ws;

    // Chebyshev fits on lambda in [aa,bb]:
    //   fF(l) = sqrt(2b*p5 - b^2*l*p5^2), fQ(l) = b*p6,  b=0.05
    const double aa = 0.06, bb = 1.85;
    const int NN = 64;
    double fF[NN], fQ[NN];
    for (int i = 0; i < NN; ++i) {
        double x = cos(M_PI * (i + 0.5) / NN);
        double lam = 0.5 * (aa + bb) + 0.5 * (bb - aa) * x;
        double m = 0.95 - 0.05 * lam;
        double p5 = 0.0, pw = 1.0;
        for (int j = 0; j < 5; ++j) { p5 += pw; pw *= m; }
        double p6 = p5 + pw;
        double p = 2.0 * 0.05 * p5 - 0.05 * 0.05 * lam * p5 * p5;
        fF[i] = sqrt(p);
        fQ[i] = 0.05 * p6;
    }
    Cheb cf;
    for (int j = 0; j <= D_CH; ++j) {
        double sF = 0.0, sQ = 0.0;
        for (int i = 0; i < NN; ++i) {
            double cw = cos(M_PI * j * (i + 0.5) / NN);
            sF += fF[i] * cw;
            sQ += fQ[i] * cw;
        }
        double sc = 2.0 / NN;
        if (j == 0) sc *= 0.5;
        cf.cF[j] = (float)(sF * sc);
        cf.cQ[j] = (float)(sQ * sc);
    }
    cf.alpha = (float)(2.0 / (bb - aa));
    cf.gamma = (float)(-(bb + aa) / (bb - aa));

    hipLaunchKernelGGL(split_kernel, dim3(256), dim3(256), 0, stream, img, ws);
    hipLaunchKernelGGL(pre_kernel, dim3(K_), dim3(512), 0, stream, w, mu, ws, cf);
    hipLaunchKernelGGL(g1_kernel, dim3(8, K_), dim3(256), 0, stream, ws);
    hipLaunchKernelGGL(g2_kernel, dim3(B_), dim3(256), 0, stream, img, mu, w, ws, out);
}

// Round 5
// 161.354 us; speedup vs baseline: 2.3983x; 1.1756x over previous
//
#include <hip/hip_runtime.h>
#include <math.h>

#define B_ 1024
#define G_ 256
#define K_ 256
#define E_ 64
#define D_CH 14   // max Chebyshev index
#define LP 40     // g1 LDS pitch (ushorts)
#define WP 72     // pre LDS pitch (ushorts), mult of 8 for 16B-aligned rows

// ws layout (floats)
#define OFF_Q6  ((size_t)0)                          // K*E*E = 1048576
#define OFF_V   ((size_t)1048576)                    // K*E
#define OFF_VT  ((size_t)1064960)                    // K*E
#define OFF_MSQ ((size_t)1081344)                    // K
#define OFF_SC  ((size_t)1081600)                    // B*K
#define OFF_U16 ((size_t)1343744)                    // ushort area (16B aligned)
#define U_WTH  ((size_t)0)           // K*80*256
#define U_WTL  ((size_t)5242880)
#define U_IMGH ((size_t)10485760)    // B*G
#define U_IMGL ((size_t)10747904)

typedef short v8s __attribute__((ext_vector_type(8)));
typedef float v4f __attribute__((ext_vector_type(4)));

struct Cheb { float cF[D_CH + 1]; float cQ[D_CH + 1]; float alpha; float gamma; };

__device__ __forceinline__ unsigned short bf16_rne(float x) {
    unsigned int u = __float_as_uint(x);
    unsigned int r = (u + 0x7FFFu + ((u >> 16) & 1u)) >> 16;
    return (unsigned short)r;
}
__device__ __forceinline__ float bf16_to_f(unsigned short h) {
    return __uint_as_float(((unsigned int)h) << 16);
}

// ---------------------------------------------------------------------------
// split: imgH/imgL bf16 hi/lo of img. grid 256, block 256.
__global__ __launch_bounds__(256) void split_kernel(const float* __restrict__ img,
                                                    float* __restrict__ ws) {
    unsigned short* wsu = (unsigned short*)(ws + OFF_U16);
    unsigned short* imgH = wsu + U_IMGH;
    unsigned short* imgL = wsu + U_IMGL;
    int i = blockIdx.x * 256 + threadIdx.x;
    float4 x = ((const float4*)img)[i];
    ushort4 h, l;
    h.x = bf16_rne(x.x); l.x = bf16_rne(x.x - bf16_to_f(h.x));
    h.y = bf16_rne(x.y); l.y = bf16_rne(x.y - bf16_to_f(h.y));
    h.z = bf16_rne(x.z); l.z = bf16_rne(x.z - bf16_to_f(h.z));
    h.w = bf16_rne(x.w); l.w = bf16_rne(x.w - bf16_to_f(h.w));
    ((ushort4*)imgH)[i] = h;
    ((ushort4*)imgL)[i] = l;
}

// ---------------------------------------------------------------------------
// pre (MFMA version): grid K, block 256 (4 waves). Wave w owns column tiles n
// in [w*16, w*16+16). Chebyshev recurrence is barrier-free (column slabs).
__global__ __launch_bounds__(256, 1) void pre_kernel(const float* __restrict__ w,
                                                     const float* __restrict__ mu,
                                                     float* __restrict__ ws, Cheb cf) {
    const int k = blockIdx.x;
    const int t = threadIdx.x;
    const int wid = t >> 6;          // n-tile index 0..3
    const int lane = t & 63;
    const int c = lane & 15, q = lane >> 4;
    const int n_ = wid * 16 + c;

    __shared__ __align__(16) unsigned short sXH[64 * WP];  // X / natW staging
    __shared__ __align__(16) unsigned short sXL[64 * WP];
    __shared__ __align__(16) unsigned short sTH[8 * 16 * WP];  // trW / T dbuf / F
    __shared__ __align__(16) unsigned short sTL[8 * 16 * WP];
    __shared__ float sMu[64];
    __shared__ float sV[64];
    __shared__ float dred[256];

    unsigned short* wsu = (unsigned short*)(ws + OFF_U16);
    unsigned short* wtTH = wsu + U_WTH;
    unsigned short* wtTL = wsu + U_WTL;

    // ---------- phase A: A = W^T W (MFMA hi/lo), v = W^T m, msq ----------
    v4f accA[4];
#pragma unroll
    for (int mi = 0; mi < 4; ++mi) accA[mi] = (v4f){0.f, 0.f, 0.f, 0.f};
    float vacc = 0.f, msqacc = 0.f;

    for (int gc = 0; gc < 4; ++gc) {
        __syncthreads();
        // stage trW chunk [e][g] hi/lo (scatter writes)
#pragma unroll
        for (int i = 0; i < 4; ++i) {
            int lin = t + 256 * i;
            int g = lin >> 4, e4 = lin & 15;
            float4 x = *(const float4*)&w[((size_t)k * G_ + gc * 64 + g) * 64 + e4 * 4];
            float xs[4] = {x.x, x.y, x.z, x.w};
#pragma unroll
            for (int j = 0; j < 4; ++j) {
                int e = e4 * 4 + j;
                unsigned short h = bf16_rne(xs[j]);
                unsigned short l = bf16_rne(xs[j] - bf16_to_f(h));
                sTH[e * WP + g] = h;
                sTL[e * WP + g] = l;
            }
        }
        if (t < 64) {
            float m = mu[(size_t)(gc * 64 + t) * K_ + k];
            sMu[t] = m;
            unsigned short h = bf16_rne(m);
            unsigned short l = bf16_rne(m - bf16_to_f(h));
            size_t gcol = ((size_t)k * 80 + 64) * 256 + gc * 64 + t;
            wtTH[gcol] = h;
            wtTL[gcol] = l;
        }
        __syncthreads();
        // A tiles (mi, wid), K = 64 g per chunk
#pragma unroll
        for (int kc = 0; kc < 2; ++kc) {
            v8s bH = *(const v8s*)&sTH[(wid * 16 + c) * WP + kc * 32 + q * 8];
            v8s bL = *(const v8s*)&sTL[(wid * 16 + c) * WP + kc * 32 + q * 8];
#pragma unroll
            for (int mi = 0; mi < 4; ++mi) {
                v8s aH = *(const v8s*)&sTH[(mi * 16 + c) * WP + kc * 32 + q * 8];
                v8s aL = *(const v8s*)&sTL[(mi * 16 + c) * WP + kc * 32 + q * 8];
                accA[mi] = __builtin_amdgcn_mfma_f32_16x16x32_bf16(aH, bH, accA[mi], 0, 0, 0);
                accA[mi] = __builtin_amdgcn_mfma_f32_16x16x32_bf16(aH, bL, accA[mi], 0, 0, 0);
                accA[mi] = __builtin_amdgcn_mfma_f32_16x16x32_bf16(aL, bH, accA[mi], 0, 0, 0);
            }
        }
        // v partial: e = lane, g-range = wid's quarter
        for (int gg = wid * 16; gg < wid * 16 + 16; ++gg) {
            float rec = bf16_to_f(sTH[lane * WP + gg]) + bf16_to_f(sTL[lane * WP + gg]);
            vacc += rec * sMu[gg];
        }
        if (t == 255) {
            for (int gg = 0; gg < 64; ++gg) msqacc += sMu[gg] * sMu[gg];
        }
    }
    dred[t] = vacc;
    if (t == 255) ws[OFF_MSQ + k] = msqacc;
    __syncthreads();
    if (t < 64) {
        float v = dred[t] + dred[t + 64] + dred[t + 128] + dred[t + 192];
        sV[t] = v;
        ws[OFF_V + (size_t)k * 64 + t] = v;
    }

    // ---------- X = alpha*A + gamma*I ; write X slabs [n][m] hi/lo ----------
    v4f Tcur[4], Told[4], Facc[4], Qacc[4];
#pragma unroll
    for (int mi = 0; mi < 4; ++mi) {
        ushort4 hv, lv;
        float xr[4];
#pragma unroll
        for (int r = 0; r < 4; ++r) {
            int m = mi * 16 + q * 4 + r;
            float id = (m == n_) ? 1.f : 0.f;
            float xv = cf.alpha * accA[mi][r] + cf.gamma * id;
            xr[r] = xv;
            Tcur[mi][r] = xv;
            Told[mi][r] = id;
            Facc[mi][r] = cf.cF[0] * id + cf.cF[1] * xv;
            Qacc[mi][r] = cf.cQ[0] * id + cf.cQ[1] * xv;
        }
        hv.x = bf16_rne(xr[0]); lv.x = bf16_rne(xr[0] - bf16_to_f(hv.x));
        hv.y = bf16_rne(xr[1]); lv.y = bf16_rne(xr[1] - bf16_to_f(hv.y));
        hv.z = bf16_rne(xr[2]); lv.z = bf16_rne(xr[2] - bf16_to_f(hv.z));
        hv.w = bf16_rne(xr[3]); lv.w = bf16_rne(xr[3] - bf16_to_f(hv.w));
        *(ushort4*)&sXH[n_ * WP + mi * 16 + q * 4] = hv;
        *(ushort4*)&sXL[n_ * WP + mi * 16 + q * 4] = lv;
    }
    __syncthreads();
    // X A-fragments -> registers (fixed for all steps). X symmetric.
    v8s xaH[4][2], xaL[4][2];
#pragma unroll
    for (int mi = 0; mi < 4; ++mi)
#pragma unroll
        for (int kc = 0; kc < 2; ++kc) {
            xaH[mi][kc] = *(const v8s*)&sXH[(mi * 16 + c) * WP + kc * 32 + q * 8];
            xaL[mi][kc] = *(const v8s*)&sXL[(mi * 16 + c) * WP + kc * 32 + q * 8];
        }

    // ---------- barrier-free Chebyshev recurrence ----------
#pragma unroll
    for (int j = 2; j <= D_CH; ++j) {
        const unsigned short* sH =
            (j == 2) ? &sXH[(wid * 16) * WP] : &sTH[((((j - 1) & 1)) * 4 + wid) * 16 * WP];
        const unsigned short* sL =
            (j == 2) ? &sXL[(wid * 16) * WP] : &sTL[((((j - 1) & 1)) * 4 + wid) * 16 * WP];
        unsigned short* dH = &sTH[((j & 1) * 4 + wid) * 16 * WP];
        unsigned short* dL = &sTL[((j & 1) * 4 + wid) * 16 * WP];
        v8s tbH[2], tbL[2];
#pragma unroll
        for (int kc = 0; kc < 2; ++kc) {
            tbH[kc] = *(const v8s*)&sH[c * WP + kc * 32 + q * 8];
            tbL[kc] = *(const v8s*)&sL[c * WP + kc * 32 + q * 8];
        }
#pragma unroll
        for (int mi = 0; mi < 4; ++mi) {
            v4f gt = (v4f){0.f, 0.f, 0.f, 0.f};
#pragma unroll
            for (int kc = 0; kc < 2; ++kc) {
                gt = __builtin_amdgcn_mfma_f32_16x16x32_bf16(xaH[mi][kc], tbH[kc], gt, 0, 0, 0);
                gt = __builtin_amdgcn_mfma_f32_16x16x32_bf16(xaH[mi][kc], tbL[kc], gt, 0, 0, 0);
                gt = __builtin_amdgcn_mfma_f32_16x16x32_bf16(xaL[mi][kc], tbH[kc], gt, 0, 0, 0);
            }
            v4f tn = 2.f * gt - Told[mi];
            Told[mi] = Tcur[mi];
            Tcur[mi] = tn;
            Facc[mi] += cf.cF[j] * tn;
            Qacc[mi] += cf.cQ[j] * tn;
            ushort4 hv, lv;
            hv.x = bf16_rne(tn[0]); lv.x = bf16_rne(tn[0] - bf16_to_f(hv.x));
            hv.y = bf16_rne(tn[1]); lv.y = bf16_rne(tn[1] - bf16_to_f(hv.y));
            hv.z = bf16_rne(tn[2]); lv.z = bf16_rne(tn[2] - bf16_to_f(hv.z));
            hv.w = bf16_rne(tn[3]); lv.w = bf16_rne(tn[3] - bf16_to_f(hv.w));
            *(ushort4*)&dH[c * WP + mi * 16 + q * 4] = hv;
            *(ushort4*)&dL[c * WP + mi * 16 + q * 4] = lv;
        }
    }

    // ---------- F slab (buf1 region, dead T13), Q6 global ----------
    unsigned short* fH = &sTH[(4 + wid) * 16 * WP];
    unsigned short* fL = &sTL[(4 + wid) * 16 * WP];
#pragma unroll
    for (int mi = 0; mi < 4; ++mi) {
        ushort4 hv, lv;
        hv.x = bf16_rne(Facc[mi][0]); lv.x = bf16_rne(Facc[mi][0] - bf16_to_f(hv.x));
        hv.y = bf16_rne(Facc[mi][1]); lv.y = bf16_rne(Facc[mi][1] - bf16_to_f(hv.y));
        hv.z = bf16_rne(Facc[mi][2]); lv.z = bf16_rne(Facc[mi][2] - bf16_to_f(hv.z));
        hv.w = bf16_rne(Facc[mi][3]); lv.w = bf16_rne(Facc[mi][3] - bf16_to_f(hv.w));
        *(ushort4*)&fH[c * WP + mi * 16 + q * 4] = hv;
        *(ushort4*)&fL[c * WP + mi * 16 + q * 4] = lv;
        *(v4f*)&ws[OFF_Q6 + (size_t)k * 4096 + n_ * 64 + mi * 16 + q * 4] = Qacc[mi];
    }

    // vtilde[f] = sum_e F[f][e] * v[e]  (row-dot of own slab)
    {
        float p = 0.f;
        const int eb = q * 16;
        v8s h0 = *(const v8s*)&fH[c * WP + eb];
        v8s h1 = *(const v8s*)&fH[c * WP + eb + 8];
        v8s l0 = *(const v8s*)&fL[c * WP + eb];
        v8s l1 = *(const v8s*)&fL[c * WP + eb + 8];
#pragma unroll
        for (int jj = 0; jj < 8; ++jj) {
            p += (bf16_to_f((unsigned short)h0[jj]) + bf16_to_f((unsigned short)l0[jj])) * sV[eb + jj];
            p += (bf16_to_f((unsigned short)h1[jj]) + bf16_to_f((unsigned short)l1[jj])) * sV[eb + 8 + jj];
        }
        p += __shfl_xor(p, 16, 64);
        p += __shfl_xor(p, 32, 64);
        if (q == 0) ws[OFF_VT + (size_t)k * 64 + n_] = p;
    }

    // ---------- Wtilde = W * F (MFMA), write wtT[k][f][g] bf16 hi/lo ----------
    v8s fbH[2], fbL[2];
#pragma unroll
    for (int kc = 0; kc < 2; ++kc) {
        fbH[kc] = *(const v8s*)&fH[c * WP + kc * 32 + q * 8];
        fbL[kc] = *(const v8s*)&fL[c * WP + kc * 32 + q * 8];
    }
    for (int rc = 0; rc < 4; ++rc) {
        __syncthreads();
        // stage natW chunk [g][e] hi/lo
#pragma unroll
        for (int i = 0; i < 4; ++i) {
            int lin = t + 256 * i;
            int g = lin >> 4, e4 = lin & 15;
            float4 x = *(const float4*)&w[((size_t)k * G_ + rc * 64 + g) * 64 + e4 * 4];
            ushort4 hv, lv;
            hv.x = bf16_rne(x.x); lv.x = bf16_rne(x.x - bf16_to_f(hv.x));
            hv.y = bf16_rne(x.y); lv.y = bf16_rne(x.y - bf16_to_f(hv.y));
            hv.z = bf16_rne(x.z); lv.z = bf16_rne(x.z - bf16_to_f(hv.z));
            hv.w = bf16_rne(x.w); lv.w = bf16_rne(x.w - bf16_to_f(hv.w));
            *(ushort4*)&sXH[g * WP + e4 * 4] = hv;
            *(ushort4*)&sXL[g * WP + e4 * 4] = lv;
        }
        __syncthreads();
#pragma unroll
        for (int mi = 0; mi < 4; ++mi) {
            v4f acc = (v4f){0.f, 0.f, 0.f, 0.f};
#pragma unroll
            for (int kc = 0; kc < 2; ++kc) {
                v8s aH = *(const v8s*)&sXH[(mi * 16 + c) * WP + kc * 32 + q * 8];
                v8s aL = *(const v8s*)&sXL[(mi * 16 + c) * WP + kc * 32 + q * 8];
                acc = __builtin_amdgcn_mfma_f32_16x16x32_bf16(aH, fbH[kc], acc, 0, 0, 0);
                acc = __builtin_amdgcn_mfma_f32_16x16x32_bf16(aH, fbL[kc], acc, 0, 0, 0);
                acc = __builtin_amdgcn_mfma_f32_16x16x32_bf16(aL, fbH[kc], acc, 0, 0, 0);
            }
            ushort4 hv, lv;
            hv.x = bf16_rne(acc[0]); lv.x = bf16_rne(acc[0] - bf16_to_f(hv.x));
            hv.y = bf16_rne(acc[1]); lv.y = bf16_rne(acc[1] - bf16_to_f(hv.y));
            hv.z = bf16_rne(acc[2]); lv.z = bf16_rne(acc[2] - bf16_to_f(hv.z));
            hv.w = bf16_rne(acc[3]); lv.w = bf16_rne(acc[3] - bf16_to_f(hv.w));
            size_t goff = ((size_t)k * 80 + n_) * 256 + rc * 64 + mi * 16 + q * 4;
            *(ushort4*)&wtTH[goff] = hv;
            *(ushort4*)&wtTL[goff] = lv;
        }
    }
}

// ---------------------------------------------------------------------------
// G1: per (b-tile 128, k): T = img * [Wtilde | mu] via bf16 hi/lo 3-MFMA;
//     score[b,k] = msq[k] - 2*T[:,64] - sum_e (T[:,e] - vtilde[e])^2
// grid (8, K), block 256 (4 waves)
__global__ __launch_bounds__(256) void g1_kernel(float* __restrict__ ws) {
    const int k = blockIdx.y;
    const int b0 = blockIdx.x * 128;
    const int t = threadIdx.x;
    const int wid = t >> 6, lane = t & 63;
    const int c = lane & 15, q = lane >> 4;
    __shared__ __align__(16) unsigned short sIH[128 * LP];
    __shared__ __align__(16) unsigned short sIL[128 * LP];
    __shared__ __align__(16) unsigned short sWH[80 * LP];
    __shared__ __align__(16) unsigned short sWL[80 * LP];

    const unsigned short* wsu = (const unsigned short*)(ws + OFF_U16);
    const unsigned short* wtTH = wsu + U_WTH;
    const unsigned short* wtTL = wsu + U_WTL;
    const unsigned short* imgH = wsu + U_IMGH;
    const unsigned short* imgL = wsu + U_IMGL;

    v4f acc[2][5];
#pragma unroll
    for (int mt = 0; mt < 2; ++mt)
#pragma unroll
        for (int nt = 0; nt < 5; ++nt) acc[mt][nt] = (v4f){0.f, 0.f, 0.f, 0.f};

    for (int gc = 0; gc < 8; ++gc) {
        __syncthreads();
#pragma unroll
        for (int i = 0; i < 2; ++i) {
            int idx = t + 256 * i;
            int r = idx >> 2, seg = idx & 3;
            size_t gsrc = (size_t)(b0 + r) * 256 + gc * 32 + seg * 8;
            *(uint4*)&sIH[r * LP + seg * 8] = *(const uint4*)&imgH[gsrc];
            *(uint4*)&sIL[r * LP + seg * 8] = *(const uint4*)&imgL[gsrc];
        }
        {
            int col = t >> 2, seg = t & 3;
            size_t gsrc = ((size_t)k * 80 + col) * 256 + gc * 32 + seg * 8;
            *(uint4*)&sWH[col * LP + seg * 8] = *(const uint4*)&wtTH[gsrc];
            *(uint4*)&sWL[col * LP + seg * 8] = *(const uint4*)&wtTL[gsrc];
            if (t < 64) {
                int idx = t + 256;
                int col2 = idx >> 2, seg2 = idx & 3;
                size_t g2 = ((size_t)k * 80 + col2) * 256 + gc * 32 + seg2 * 8;
                *(uint4*)&sWH[col2 * LP + seg2 * 8] = *(const uint4*)&wtTH[g2];
                *(uint4*)&sWL[col2 * LP + seg2 * 8] = *(const uint4*)&wtTL[g2];
            }
        }
        __syncthreads();
        v8s aH[2], aL[2];
#pragma unroll
        for (int mt = 0; mt < 2; ++mt) {
            int row = wid * 32 + mt * 16 + c;
            aH[mt] = *(const v8s*)&sIH[row * LP + q * 8];
            aL[mt] = *(const v8s*)&sIL[row * LP + q * 8];
        }
#pragma unroll
        for (int nt = 0; nt < 5; ++nt) {
            int colr = nt * 16 + c;
            v8s bH = *(const v8s*)&sWH[colr * LP + q * 8];
            v8s bL = *(const v8s*)&sWL[colr * LP + q * 8];
#pragma unroll
            for (int mt = 0; mt < 2; ++mt) {
                acc[mt][nt] = __builtin_amdgcn_mfma_f32_16x16x32_bf16(aH[mt], bH, acc[mt][nt], 0, 0, 0);
                acc[mt][nt] = __builtin_amdgcn_mfma_f32_16x16x32_bf16(aH[mt], bL, acc[mt][nt], 0, 0, 0);
                acc[mt][nt] = __builtin_amdgcn_mfma_f32_16x16x32_bf16(aL[mt], bH, acc[mt][nt], 0, 0, 0);
            }
        }
    }
    float msq = ws[OFF_MSQ + k];
    float vtr[4];
#pragma unroll
    for (int nt = 0; nt < 4; ++nt)
        vtr[nt] = ws[OFF_VT + (size_t)k * 64 + nt * 16 + c];
#pragma unroll
    for (int mt = 0; mt < 2; ++mt) {
        float tot[4];
#pragma unroll
        for (int r = 0; r < 4; ++r) tot[r] = 0.f;
#pragma unroll
        for (int nt = 0; nt < 4; ++nt)
#pragma unroll
            for (int r = 0; r < 4; ++r) {
                float d = acc[mt][nt][r] - vtr[nt];
                tot[r] += d * d;
            }
        if (c == 0) {
#pragma unroll
            for (int r = 0; r < 4; ++r) tot[r] += 2.f * acc[mt][4][r];
        }
#pragma unroll
        for (int r = 0; r < 4; ++r) {
            tot[r] += __shfl_xor(tot[r], 1, 64);
            tot[r] += __shfl_xor(tot[r], 2, 64);
            tot[r] += __shfl_xor(tot[r], 4, 64);
            tot[r] += __shfl_xor(tot[r], 8, 64);
        }
        if (c == 0) {
#pragma unroll
            for (int r = 0; r < 4; ++r) {
                int row = b0 + wid * 32 + mt * 16 + q * 4 + r;
                ws[OFF_SC + (size_t)row * K_ + k] = msq - tot[r];
            }
        }
    }
}

// ---------------------------------------------------------------------------
// G2: per b: argmin_k score, then u = W_k^T img - v ; z6 = Q6 u ; y = W_k z6 + m_k
__global__ __launch_bounds__(256) void g2_kernel(const float* __restrict__ img,
                                                 const float* __restrict__ mu,
                                                 const float* __restrict__ w,
                                                 const float* __restrict__ ws,
                                                 float* __restrict__ out) {
    const int b = blockIdx.x;
    const int t = threadIdx.x;
    __shared__ float rv[4];
    __shared__ int ri[4];
    __shared__ int skbest;
    __shared__ float simg[256];
    __shared__ float up[4][64];
    __shared__ float su[64];
    __shared__ float sz[64];

    float val = ws[OFF_SC + (size_t)b * K_ + t];
    int idx = t;
#pragma unroll
    for (int off = 32; off >= 1; off >>= 1) {
        float ov = __shfl_down(val, off, 64);
        int oi = __shfl_down(idx, off, 64);
        if (ov < val || (ov == val && oi < idx)) { val = ov; idx = oi; }
    }
    if ((t & 63) == 0) { rv[t >> 6] = val; ri[t >> 6] = idx; }
    simg[t] = img[(size_t)b * G_ + t];
    __syncthreads();
    if (t == 0) {
        float bv = rv[0]; int bi = ri[0];
#pragma unroll
        for (int i = 1; i < 4; ++i)
            if (rv[i] < bv || (rv[i] == bv && ri[i] < bi)) { bv = rv[i]; bi = ri[i]; }
        skbest = bi;
    }
    __syncthreads();
    const int kb = skbest;
    const int e = t & 63, p = t >> 6;

    {
        float acc = 0.f;
        const float* wcol = w + ((size_t)kb * G_ + p * 64) * E_ + e;
        for (int g = 0; g < 64; ++g) acc += wcol[(size_t)g * E_] * simg[p * 64 + g];
        up[p][e] = acc;
    }
    __syncthreads();
    if (t < 64)
        su[t] = up[0][t] + up[1][t] + up[2][t] + up[3][t] - ws[OFF_V + (size_t)kb * 64 + t];
    __syncthreads();
    {
        float acc = 0.f;
        const float* qrow = ws + OFF_Q6 + (size_t)kb * 4096 + e * 64 + p * 16;
#pragma unroll
        for (int f = 0; f < 16; ++f) acc += qrow[f] * su[p * 16 + f];
        up[p][e] = acc;
    }
    __syncthreads();
    if (t < 64) sz[t] = up[0][t] + up[1][t] + up[2][t] + up[3][t];
    __syncthreads();
    {
        float acc = 0.f;
        const float* wrow = w + ((size_t)kb * G_ + t) * E_;
#pragma unroll 8
        for (int e2 = 0; e2 < 64; ++e2) acc += wrow[e2] * sz[e2];
        out[(size_t)b * G_ + t] = acc + mu[(size_t)t * K_ + kb];
    }
}

// ---------------------------------------------------------------------------
extern "C" void kernel_launch(void* const* d_in, const int* in_sizes, int n_in,
                              void* d_out, int out_size, void* d_ws, size_t ws_size,
                              hipStream_t stream) {
    const float* img = (const float*)d_in[0];
    const float* mu  = (const float*)d_in[1];
    const float* w   = (const float*)d_in[2];
    float* out = (float*)d_out;
    float* ws = (float*)d_ws;

    const double aa = 0.06, bb = 1.85;
    const int NN = 64;
    double fF[NN], fQ[NN];
    for (int i = 0; i < NN; ++i) {
        double x = cos(M_PI * (i + 0.5) / NN);
        double lam = 0.5 * (aa + bb) + 0.5 * (bb - aa) * x;
        double m = 0.95 - 0.05 * lam;
        double p5 = 0.0, pw = 1.0;
        for (int j = 0; j < 5; ++j) { p5 += pw; pw *= m; }
        double p6 = p5 + pw;
        double p = 2.0 * 0.05 * p5 - 0.05 * 0.05 * lam * p5 * p5;
        fF[i] = sqrt(p);
        fQ[i] = 0.05 * p6;
    }
    Cheb cf;
    for (int j = 0; j <= D_CH; ++j) {
        double sF = 0.0, sQ = 0.0;
        for (int i = 0; i < NN; ++i) {
            double cw = cos(M_PI * j * (i + 0.5) / NN);
            sF += fF[i] * cw;
            sQ += fQ[i] * cw;
        }
        double sc = 2.0 / NN;
        if (j == 0) sc *= 0.5;
        cf.cF[j] = (float)(sF * sc);
        cf.cQ[j] = (float)(sQ * sc);
    }
    cf.alpha = (float)(2.0 / (bb - aa));
    cf.gamma = (float)(-(bb + aa) / (bb - aa));

    hipLaunchKernelGGL(split_kernel, dim3(256), dim3(256), 0, stream, img, ws);
    hipLaunchKernelGGL(pre_kernel, dim3(K_), dim3(256), 0, stream, w, mu, ws, cf);
    hipLaunchKernelGGL(g1_kernel, dim3(8, K_), dim3(256), 0, stream, ws);
    hipLaunchKernelGGL(g2_kernel, dim3(B_), dim3(256), 0, stream, img, mu, w, ws, out);
}